// Round 16
// baseline (1922.246 us; speedup 1.0000x reference)
//
#include <hip/hip_runtime.h>
#include <cstdint>

#define D 300
#define MAXLEN 50
#define K1P 320    // bf16 row stride for aggbf/hb/cmb (640B); gemm1 K. cols 300-317 = combo counts
#define H1 600     // hidden dim
#define H1P 608    // hid bf16 row stride (1216B); gemm2 K
#define W1ROWS 640 // padded rows for W1t (5 col-tiles of 128)
#define W2ROWS 384 // padded rows for W2t (3 col-tiles of 128)

typedef __attribute__((ext_vector_type(8))) short s16x8;
typedef __attribute__((ext_vector_type(4))) short s16x4;
typedef __attribute__((ext_vector_type(4))) float f32x4;
typedef __attribute__((ext_vector_type(2))) float f32x2;
typedef __attribute__((ext_vector_type(4))) int i32x4;

__device__ __forceinline__ unsigned short f2b(float f) {
  uint32_t u = __builtin_bit_cast(uint32_t, f);
  u += 0x7FFFu + ((u >> 16) & 1u);
  return (unsigned short)(u >> 16);
}
__device__ __forceinline__ float b2f(unsigned short s) {
  return __builtin_bit_cast(float, (uint32_t)s << 16);
}
__device__ __forceinline__ void gld_lds16(const void* g, void* l) {
  __builtin_amdgcn_global_load_lds((const __attribute__((address_space(1))) void*)g,
                                   (__attribute__((address_space(3))) void*)l, 16, 0, 0);
}

// ---------------- combo embedding table: cmb[a*3+b] = xe1[a] + xe2[b] ----------------
__global__ void k_cmb(const float* __restrict__ xe1, const float* __restrict__ xe2,
                      unsigned short* __restrict__ cmb, int total /* 360*75 */) {
  int i = blockIdx.x * blockDim.x + threadIdx.x;
  if (i >= total) return;
  int c = i / 75, d = (i - c * 75) * 4;
  int a = c / 3, b = c - a * 3;
  s16x4 out;
#pragma unroll
  for (int j = 0; j < 4; ++j) out[j] = (short)f2b(xe1[(size_t)a * D + d + j] + xe2[(size_t)b * D + d + j]);
  *(s16x4*)(cmb + (size_t)c * K1P + d) = out;
}

// per-node combo id
__global__ void k_cid(const int* __restrict__ x, int* __restrict__ cid, int N) {
  int i = blockIdx.x * blockDim.x + threadIdx.x;
  if (i < N) cid[i] = x[2 * i] * 3 + x[2 * i + 1];
}

__global__ void k_count(const int* __restrict__ key, int* __restrict__ cnt, int n) {
  int i = blockIdx.x * blockDim.x + threadIdx.x;
  if (i < n) atomicAdd(&cnt[key[i]], 1);
}

// ---------------- hierarchical exclusive scan (1024 elems/block) ----------------
__global__ void k_scan1(const int* __restrict__ in, int* __restrict__ part, int n) {
  __shared__ int red[256];
  int tid = threadIdx.x;
  int base = blockIdx.x * 1024 + tid * 4;
  i32x4 v = {0, 0, 0, 0};
  if (base + 3 < n) v = *(const i32x4*)(in + base);
  else {
#pragma unroll
    for (int k = 0; k < 4; ++k) v[k] = (base + k < n) ? in[base + k] : 0;
  }
  int s = v[0] + v[1] + v[2] + v[3];
  red[tid] = s;
  __syncthreads();
  for (int off = 1; off < 256; off <<= 1) {
    int t = (tid >= off) ? red[tid - off] : 0;
    __syncthreads();
    red[tid] += t;
    __syncthreads();
  }
  if (tid == 255) part[blockIdx.x] = red[255];
}

__global__ void k_scan2(int* __restrict__ part, int P) {
  __shared__ int sm[1024];
  int tid = threadIdx.x;
  int v = (tid < P) ? part[tid] : 0;
  sm[tid] = v;
  __syncthreads();
  for (int off = 1; off < 1024; off <<= 1) {
    int t = (tid >= off) ? sm[tid - off] : 0;
    __syncthreads();
    sm[tid] += t;
    __syncthreads();
  }
  if (tid < P) part[tid] = sm[tid] - v;
  if (tid == 1023) part[P] = sm[1023];
}

__global__ void k_scan3(const int* __restrict__ in, const int* __restrict__ part,
                        int* __restrict__ out, int n, int P) {
  __shared__ int red[256];
  int tid = threadIdx.x;
  int base = blockIdx.x * 1024 + tid * 4;
  i32x4 v = {0, 0, 0, 0};
  if (base + 3 < n) v = *(const i32x4*)(in + base);
  else {
#pragma unroll
    for (int k = 0; k < 4; ++k) v[k] = (base + k < n) ? in[base + k] : 0;
  }
  int s = v[0] + v[1] + v[2] + v[3];
  red[tid] = s;
  __syncthreads();
  for (int off = 1; off < 256; off <<= 1) {
    int t = (tid >= off) ? red[tid - off] : 0;
    __syncthreads();
    red[tid] += t;
    __syncthreads();
  }
  int pre = red[tid] - s + part[blockIdx.x];
  if (base < n) out[base] = pre;
  if (base + 1 < n) out[base + 1] = pre + v[0];
  if (base + 2 < n) out[base + 2] = pre + v[0] + v[1];
  if (base + 3 < n) out[base + 3] = pre + v[0] + v[1] + v[2];
  if (blockIdx.x == 0 && tid == 0) out[n] = part[P];
}

// dst-sorted node ids (ssrc), layer0 row ids (scid); per-dst combo histogram (cnt18)
__global__ void k_fill(const int* __restrict__ src, const int* __restrict__ dst,
                       const int* __restrict__ ea, const int* __restrict__ cid,
                       int* __restrict__ cur, const int* __restrict__ offs,
                       int* __restrict__ ssrc, int* __restrict__ scid,
                       int* __restrict__ cnt18, int E_) {
  int e = blockIdx.x * blockDim.x + threadIdx.x;
  if (e >= E_) return;
  int d = dst[e];
  int s = src[e];
  int p = atomicAdd(&cur[d], 1);
  int pos = offs[d] + p;
  ssrc[pos] = s;
  scid[pos] = cid[s];
  int co = ea[2 * e] * 3 + ea[2 * e + 1];
  atomicAdd(&cnt18[d * 18 + co], 1);
}

// write combo counts (bf16) into aggbf cols 300..317 (+1 on combo 12 = self loop); zero 318/319
__global__ void k_cnt18bf(const int* __restrict__ cnt18, unsigned short* __restrict__ aggbf, int N) {
  int idx = blockIdx.x * blockDim.x + threadIdx.x;
  if (idx >= N * 10) return;
  int i = idx / 10, j = idx - i * 10;
  uint32_t o = 0;
  if (j < 9) {
    int c0 = cnt18[i * 18 + 2 * j] + (2 * j == 12 ? 1 : 0);
    int c1 = cnt18[i * 18 + 2 * j + 1];
    o = (uint32_t)f2b((float)c0) | ((uint32_t)f2b((float)c1) << 16);
  }
  *(uint32_t*)(aggbf + (size_t)i * K1P + D + j * 2) = o;
}

// ecW1 rows of W1t: W1t[n][300+k18] = bf16( sum_d (ee1[l][k18/3][d]+ee2[l][k18%3][d]) * W1[l][d][n] )
__global__ void k_ecw1(const float* __restrict__ ee1, const float* __restrict__ ee2,
                       const float* __restrict__ W1, unsigned short* __restrict__ W1tA,
                       int L_, int total /* L*600*18 */) {
  int idx = blockIdx.x * blockDim.x + threadIdx.x;
  if (idx >= total) return;
  int k18 = idx % 18;
  int n = (idx / 18) % H1;
  int l = idx / (18 * H1);
  const float* e1 = ee1 + ((size_t)l * 6 + k18 / 3) * D;
  const float* e2 = ee2 + ((size_t)l * 3 + k18 % 3) * D;
  const float* w = W1 + (size_t)l * D * H1 + n;
  float s = 0.f;
  for (int d = 0; d < D; ++d) s += (e1[d] + e2[d]) * w[(size_t)d * H1];
  W1tA[(size_t)l * W1ROWS * K1P + (size_t)n * K1P + D + k18] = f2b(s);
}

// ---------------- aggregation: one wave per node; 8B-vectorized h-gathers ----------------
template <int FUSE>
__global__ void k_agg(const unsigned short* __restrict__ hin, const int* __restrict__ ridx,
                      const int* __restrict__ offs, const float* __restrict__ scale,
                      const float* __restrict__ shift, const int* __restrict__ selfcid,
                      unsigned short* __restrict__ aggbf, int N) {
  int w = (int)((blockIdx.x * blockDim.x + threadIdx.x) >> 6);
  if (w >= N) return;
  int lane = threadIdx.x & 63;
  const bool act1 = lane < 11;
  const int e0 = lane * 4;                          // elem offset, 8B aligned
  const int e1 = (act1 ? (64 + lane) : lane) * 4;   // clamped for inactive lanes
  float sc0[4], sh0[4], sc1[4], sh1[4];
  if (FUSE) {
    f32x4 a = *(const f32x4*)(scale + e0);
    f32x4 b = *(const f32x4*)(shift + e0);
    f32x4 c = *(const f32x4*)(scale + e1);
    f32x4 d = *(const f32x4*)(shift + e1);
#pragma unroll
    for (int j = 0; j < 4; ++j) { sc0[j] = a[j]; sh0[j] = b[j]; sc1[j] = c[j]; sh1[j] = d[j]; }
  } else {
#pragma unroll
    for (int j = 0; j < 4; ++j) { sc0[j] = sc1[j] = sh0[j] = sh1[j] = 0.f; }
  }
  int beg = offs[w], end = offs[w + 1];
  int wrow = FUSE ? w : selfcid[w];
  float s0[4], s1[4];
  {
    const unsigned short* rp = hin + (size_t)wrow * K1P;
    s16x4 v0 = *(const s16x4*)(rp + e0);
    s16x4 v1 = *(const s16x4*)(rp + e1);
#pragma unroll
    for (int j = 0; j < 4; ++j) {
      float a = b2f((unsigned short)v0[j]);
      float b = b2f((unsigned short)v1[j]);
      if (FUSE) { a = fmaxf(a * sc0[j] + sh0[j], 0.f); b = fmaxf(b * sc1[j] + sh1[j], 0.f); }
      s0[j] = a; s1[j] = b;
    }
  }
  int j = beg;
  for (; j + 4 <= end; j += 4) {
    const unsigned short* p0 = hin + (size_t)ridx[j] * K1P;
    const unsigned short* p1 = hin + (size_t)ridx[j + 1] * K1P;
    const unsigned short* p2 = hin + (size_t)ridx[j + 2] * K1P;
    const unsigned short* p3 = hin + (size_t)ridx[j + 3] * K1P;
    s16x4 a0 = *(const s16x4*)(p0 + e0), b0 = *(const s16x4*)(p0 + e1);
    s16x4 a1 = *(const s16x4*)(p1 + e0), b1 = *(const s16x4*)(p1 + e1);
    s16x4 a2 = *(const s16x4*)(p2 + e0), b2 = *(const s16x4*)(p2 + e1);
    s16x4 a3 = *(const s16x4*)(p3 + e0), b3 = *(const s16x4*)(p3 + e1);
#pragma unroll
    for (int k = 0; k < 4; ++k) {
      float x0 = b2f((unsigned short)a0[k]), x1 = b2f((unsigned short)a1[k]);
      float x2 = b2f((unsigned short)a2[k]), x3 = b2f((unsigned short)a3[k]);
      float y0 = b2f((unsigned short)b0[k]), y1 = b2f((unsigned short)b1[k]);
      float y2 = b2f((unsigned short)b2[k]), y3 = b2f((unsigned short)b3[k]);
      if (FUSE) {
        x0 = fmaxf(x0 * sc0[k] + sh0[k], 0.f); x1 = fmaxf(x1 * sc0[k] + sh0[k], 0.f);
        x2 = fmaxf(x2 * sc0[k] + sh0[k], 0.f); x3 = fmaxf(x3 * sc0[k] + sh0[k], 0.f);
        y0 = fmaxf(y0 * sc1[k] + sh1[k], 0.f); y1 = fmaxf(y1 * sc1[k] + sh1[k], 0.f);
        y2 = fmaxf(y2 * sc1[k] + sh1[k], 0.f); y3 = fmaxf(y3 * sc1[k] + sh1[k], 0.f);
      }
      s0[k] += (x0 + x1) + (x2 + x3);
      s1[k] += (y0 + y1) + (y2 + y3);
    }
  }
  for (; j < end; ++j) {
    const unsigned short* rp = hin + (size_t)ridx[j] * K1P;
    s16x4 v0 = *(const s16x4*)(rp + e0);
    s16x4 v1 = *(const s16x4*)(rp + e1);
#pragma unroll
    for (int k = 0; k < 4; ++k) {
      float a = b2f((unsigned short)v0[k]);
      float b = b2f((unsigned short)v1[k]);
      if (FUSE) { a = fmaxf(a * sc0[k] + sh0[k], 0.f); b = fmaxf(b * sc1[k] + sh1[k], 0.f); }
      s0[k] += a;
      s1[k] += b;
    }
  }
  s16x4 o0, o1;
#pragma unroll
  for (int k = 0; k < 4; ++k) { o0[k] = (short)f2b(s0[k]); o1[k] = (short)f2b(s1[k]); }
  *(s16x4*)(aggbf + (size_t)w * K1P + e0) = o0;
  if (act1) *(s16x4*)(aggbf + (size_t)w * K1P + e1) = o1;
}

// transpose+convert weights: Wt[n][k] = bf16(W[k][n]), zero-padded
__global__ void k_wconv(const float* __restrict__ W, unsigned short* __restrict__ Wt,
                        int K, int Nout, int Kp, int total) {
  int idx = blockIdx.x * blockDim.x + threadIdx.x;
  if (idx >= total) return;
  int n = idx / Kp, k = idx - n * Kp;
  float v = (k < K && n < Nout) ? W[(size_t)k * Nout + n] : 0.f;
  Wt[idx] = f2b(v);
}

// ---------------- reg-A + 3-buffer-B counted-vmcnt MFMA GEMM (R16 = R14 fixed) ----------------
// R14 failed from VGPR spill: launch_bounds(256,4) capped VGPR at 128 but the compiler
// allocated 64 and spilled acc (WRITE_SIZE 355MB scratch). Fix: (256,3) -> cap ~170,
// design needs ~130. Mechanism: A-frags are perfectly coalesced per-wave global loads
// (16 rows x 64B/frag), so A skips LDS entirely -> halves LDS traffic (the diagnosed
// limiter: ~196 B/cy demand vs ~128-256 B/cy pipe). B keeps the proven 3-buffer
// gld_lds pipeline. vmcnt: body t issues A(t+2)x4 + B(t+2)x2 after MFMA; before
// body t, allowed in-flight = A(t+1)+B(t+1) = 6 -> vmcnt(6); tail vmcnt(0).
template <int K, int EPI>
__global__ __launch_bounds__(256, 3) void k_gemm(
    const unsigned short* __restrict__ A, const unsigned short* __restrict__ Bt,
    const float* __restrict__ bias, unsigned short* __restrict__ Cb,
    float* __restrict__ sums, int M, int Nout, int ldc, int CT) {
  constexpr int T = K / 32;
  __shared__ __align__(16) unsigned short Bsm[3 * 4096];  // 3 x [128r][4 slots][8] = 24 KB

  int nwg = gridDim.x;
  int q = nwg >> 3, r8 = nwg & 7;
  int xcd = blockIdx.x & 7, oidx = blockIdx.x >> 3;
  int wid = (xcd < r8 ? xcd * (q + 1) : r8 * (q + 1) + (xcd - r8) * q) + oidx;
  int ct = wid % CT, rt = wid / CT;
  const int rowBase = rt * 128, colBase = ct * 128;

  const int tid = threadIdx.x, lane = tid & 63, wave = tid >> 6;
  const int wm = wave >> 1, wn = wave & 1;
  const int l15 = lane & 15, lg = lane >> 4;

  const unsigned short* Arow[4];
#pragma unroll
  for (int mi = 0; mi < 4; ++mi) {
    int r = rowBase + wm * 64 + mi * 16 + l15;
    if (r >= M) r = M - 1;
    Arow[mi] = A + (size_t)r * K + lg * 8;
  }

  auto stageB = [&](int s, int t) {
#pragma unroll
    for (int i = 0; i < 2; ++i) {
      int u = tid + i * 256;
      int rr = u >> 2;
      int cdat = (u & 3) ^ ((rr >> 1) & 3);  // inverse-swizzled source chunk
      gld_lds16(Bt + (size_t)(colBase + rr) * K + t * 32 + cdat * 8, Bsm + s * 4096 + u * 8);
    }
  };

  s16x8 aset[2][4];
  // prologue: A(0)->set0, B(0); A(1)->set1, B(1)   (FIFO: A0x4 B0x2 A1x4 B1x2)
#pragma unroll
  for (int mi = 0; mi < 4; ++mi) aset[0][mi] = *(const s16x8*)(Arow[mi]);
  stageB(0, 0);
#pragma unroll
  for (int mi = 0; mi < 4; ++mi) aset[1][mi] = *(const s16x8*)(Arow[mi] + 32);
  stageB(1, 1);

  f32x4 acc[4][4] = {};
#pragma unroll
  for (int t = 0; t < T; ++t) {
    if (t + 1 < T) asm volatile("s_waitcnt vmcnt(6)" ::: "memory");
    else           asm volatile("s_waitcnt vmcnt(0)" ::: "memory");
    __builtin_amdgcn_s_barrier();
    __builtin_amdgcn_sched_barrier(0);
    const unsigned short* bB = Bsm + (t % 3) * 4096;
    s16x8 bf[4];
#pragma unroll
    for (int i = 0; i < 4; ++i) {
      int rb = wn * 64 + i * 16 + l15;
      bf[i] = *(const s16x8*)(bB + ((size_t)rb * 4 + (lg ^ ((rb >> 1) & 3))) * 8);
    }
#pragma unroll
    for (int mi = 0; mi < 4; ++mi)
#pragma unroll
      for (int ni = 0; ni < 4; ++ni)
        acc[mi][ni] = __builtin_amdgcn_mfma_f32_16x16x32_bf16(aset[t & 1][mi], bf[ni], acc[mi][ni], 0, 0, 0);
    if (t + 2 < T) {  // issue next stages AFTER the MFMAs consume aset[t&1]
#pragma unroll
      for (int mi = 0; mi < 4; ++mi) aset[t & 1][mi] = *(const s16x8*)(Arow[mi] + (t + 2) * 32);
      stageB((t + 2) % 3, t + 2);
    }
  }

  // epilogue: direct u16 stores
  float bnS[4] = {0.f, 0.f, 0.f, 0.f}, bnQ[4] = {0.f, 0.f, 0.f, 0.f};
#pragma unroll
  for (int ni = 0; ni < 4; ++ni) {
    int col = colBase + wn * 64 + ni * 16 + l15;
    if (col >= (EPI ? ldc : Nout)) continue;  // gemm2: skip dead pad cols
    bool inN = col < Nout;
    float bv = inN ? bias[col] : 0.f;
#pragma unroll
    for (int mi = 0; mi < 4; ++mi) {
      int row0 = rowBase + wm * 64 + mi * 16 + lg * 4;
#pragma unroll
      for (int rr = 0; rr < 4; ++rr) {
        int row = row0 + rr;
        if (row < M) {
          float v = inN ? acc[mi][ni][rr] + bv : 0.f;
          if (EPI) v = fmaxf(v, 0.f);
          else { bnS[ni] += v; bnQ[ni] += v * v; }
          Cb[(size_t)row * ldc + col] = f2b(v);
        }
      }
    }
  }
  if (!EPI) {
#pragma unroll
    for (int ni = 0; ni < 4; ++ni) {
      float cs = bnS[ni], cq = bnQ[ni];
      cs += __shfl_xor(cs, 16); cq += __shfl_xor(cq, 16);
      cs += __shfl_xor(cs, 32); cq += __shfl_xor(cq, 32);
      int col = colBase + wn * 64 + ni * 16 + l15;
      if (lg == 0 && col < Nout) {
        atomicAdd(&sums[col], cs);
        atomicAdd(&sums[D + col], cq);
      }
    }
  }
}

// ---------------- BatchNorm finalize ----------------
__global__ void k_bnfinal(const float* __restrict__ sums, const float* __restrict__ sumsq,
                          const float* __restrict__ gamma, const float* __restrict__ beta,
                          float* __restrict__ scale, float* __restrict__ shift, int N) {
  int c = threadIdx.x;
  if (c >= D) return;
  float inv = 1.f / (float)N;
  float mean = sums[c] * inv;
  float var = sumsq[c] * inv - mean * mean;
  if (var < 0.f) var = 0.f;
  float sc = gamma[c] * rsqrtf(var + 1e-5f);
  scale[c] = sc;
  shift[c] = beta[c] - mean * sc;
}

// ---------------- outputs (BN of last layer fused; no relu), vectorized ----------------
__global__ void k_pool(const unsigned short* __restrict__ hb, const float* __restrict__ scale,
                       const float* __restrict__ shift, const int* __restrict__ gs,
                       const int* __restrict__ gc, float* __restrict__ pooled, int total /* B*75 */) {
  int gid = blockIdx.x * blockDim.x + threadIdx.x;
  if (gid >= total) return;
  int g = gid / 75, c4 = (gid - g * 75) * 4;
  int start = gs[g], cnt = gc[g];
  f32x4 s = {0.f, 0.f, 0.f, 0.f};
  for (int i = 0; i < cnt; ++i) {
    s16x4 in = *(const s16x4*)(hb + (size_t)(start + i) * K1P + c4);
#pragma unroll
    for (int j = 0; j < 4; ++j) s[j] += b2f((unsigned short)in[j]);
  }
  f32x4 sc = *(const f32x4*)(scale + c4);
  f32x4 sh = *(const f32x4*)(shift + c4);
  float dv = (cnt > 0) ? (float)cnt : 1.f;
  f32x4 out;
#pragma unroll
  for (int j = 0; j < 4; ++j) out[j] = (s[j] * sc[j] + sh[j] * (float)cnt) / dv;
  *(f32x4*)(pooled + (size_t)g * D + c4) = out;
}

__global__ void k_nf(const unsigned short* __restrict__ hb, const float* __restrict__ scale,
                     const float* __restrict__ shift, const int* __restrict__ gs,
                     const int* __restrict__ gc, float* __restrict__ nf, float* __restrict__ mask) {
  int g = blockIdx.x;
  int start = gs[g], cnt = gc[g];
  int lim = cnt < MAXLEN ? cnt : MAXLEN;
  for (int idx = threadIdx.x; idx < MAXLEN * 75; idx += 256) {
    int p = idx / 75;
    int c4 = (idx - p * 75) * 4;
    f32x4 v = {0.f, 0.f, 0.f, 0.f};
    if (p < lim) {
      s16x4 in = *(const s16x4*)(hb + (size_t)(start + p) * K1P + c4);
      f32x4 sc = *(const f32x4*)(scale + c4);
      f32x4 sh = *(const f32x4*)(shift + c4);
#pragma unroll
      for (int j = 0; j < 4; ++j) v[j] = b2f((unsigned short)in[j]) * sc[j] + sh[j];
    }
    *(f32x4*)(nf + (size_t)g * (MAXLEN * D) + p * D + c4) = v;
  }
  if (threadIdx.x < MAXLEN) mask[(size_t)g * MAXLEN + threadIdx.x] = (threadIdx.x < lim) ? 1.f : 0.f;
}

extern "C" void kernel_launch(void* const* d_in, const int* in_sizes, int n_in,
                              void* d_out, int out_size, void* d_ws, size_t ws_size,
                              hipStream_t stream) {
  const int* x      = (const int*)d_in[0];
  const int* ei     = (const int*)d_in[1];   // [2][E]: src = ei, dst = ei+E
  const int* ea     = (const int*)d_in[2];   // [E][2]
  const int* batch  = (const int*)d_in[3];
  const float* xe1  = (const float*)d_in[5];
  const float* xe2  = (const float*)d_in[6];
  const float* ee1  = (const float*)d_in[7]; // [L][6][D]
  const float* ee2  = (const float*)d_in[8]; // [L][3][D]
  const float* W1   = (const float*)d_in[9];
  const float* b1   = (const float*)d_in[10];
  const float* W2   = (const float*)d_in[11];
  const float* b2   = (const float*)d_in[12];
  const float* gamma = (const float*)d_in[13];
  const float* beta  = (const float*)d_in[14];

  const int N = in_sizes[0] / 2;
  const int E = in_sizes[1] / 2;
  const int L = in_sizes[9] / (D * 2 * D);
  const int B = out_size / (D + MAXLEN * D + MAXLEN);

  char* ws = (char*)d_ws;
  size_t off = 0;
  auto alloc = [&](size_t bytes) -> void* {
    void* p = ws + off;
    off += (bytes + 255) & ~(size_t)255;
    return p;
  };
  unsigned short* aggbf = (unsigned short*)alloc((size_t)N * K1P * 2);
  unsigned short* hb    = (unsigned short*)alloc((size_t)N * K1P * 2);
  unsigned short* hid   = (unsigned short*)alloc((size_t)N * H1P * 2);
  unsigned short* cmb   = (unsigned short*)alloc((size_t)360 * K1P * 2);
  unsigned short* W1tA = (unsigned short*)alloc((size_t)L * W1ROWS * K1P * 2);
  unsigned short* W2tA = (unsigned short*)alloc((size_t)L * W2ROWS * H1P * 2);
  int* cnt    = (int*)alloc((size_t)N * 4);
  int* cur    = (int*)alloc((size_t)N * 4);
  int* offs   = (int*)alloc((size_t)(N + 1) * 4);
  int* cid    = (int*)alloc((size_t)N * 4);
  int* cnt18  = (int*)alloc((size_t)N * 18 * 4);
  int* ssrc   = (int*)alloc((size_t)E * 4);
  int* scid   = (int*)alloc((size_t)E * 4);
  int* gc     = (int*)alloc((size_t)B * 4);
  int* gs     = (int*)alloc((size_t)(B + 1) * 4);
  int* part   = (int*)alloc(1024 * 4);
  float* sumsA = (float*)alloc((size_t)L * 2 * D * 4);
  float* scale = (float*)alloc(2 * D * 4);  // scale | shift

  hipMemsetAsync(cnt, 0, (size_t)N * 4, stream);
  hipMemsetAsync(cur, 0, (size_t)N * 4, stream);
  hipMemsetAsync(gc, 0, (size_t)B * 4, stream);
  hipMemsetAsync(cnt18, 0, (size_t)N * 18 * 4, stream);
  hipMemsetAsync(sumsA, 0, (size_t)L * 2 * D * 4, stream);

  k_cmb<<<(360 * 75 + 255) / 256, 256, 0, stream>>>(xe1, xe2, cmb, 360 * 75);
  k_cid<<<(N + 255) / 256, 256, 0, stream>>>(x, cid, N);
  k_count<<<(E + 255) / 256, 256, 0, stream>>>(ei + E, cnt, E);
  {
    int P = (N + 1023) / 1024;
    k_scan1<<<P, 256, 0, stream>>>(cnt, part, N);
    k_scan2<<<1, 1024, 0, stream>>>(part, P);
    k_scan3<<<P, 256, 0, stream>>>(cnt, part, offs, N, P);
  }
  k_fill<<<(E + 255) / 256, 256, 0, stream>>>(ei, ei + E, ea, cid, cur, offs, ssrc, scid, cnt18, E);
  k_cnt18bf<<<(N * 10 + 255) / 256, 256, 0, stream>>>(cnt18, aggbf, N);
  k_count<<<(N + 255) / 256, 256, 0, stream>>>(batch, gc, N);
  {
    int P = (B + 1023) / 1024;
    k_scan1<<<P, 256, 0, stream>>>(gc, part, B);
    k_scan2<<<1, 1024, 0, stream>>>(part, P);
    k_scan3<<<P, 256, 0, stream>>>(gc, part, gs, B, P);
  }
  for (int l = 0; l < L; ++l) {
    k_wconv<<<(W1ROWS * K1P + 255) / 256, 256, 0, stream>>>(
        W1 + (size_t)l * D * H1, W1tA + (size_t)l * W1ROWS * K1P, D, H1, K1P, W1ROWS * K1P);
    k_wconv<<<(W2ROWS * H1P + 255) / 256, 256, 0, stream>>>(
        W2 + (size_t)l * H1 * D, W2tA + (size_t)l * W2ROWS * H1P, H1, D, H1P, W2ROWS * H1P);
  }
  k_ecw1<<<(L * H1 * 18 + 255) / 256, 256, 0, stream>>>(ee1, ee2, W1, W1tA, L, L * H1 * 18);

  const int RT = (N + 127) / 128;
  for (int l = 0; l < L; ++l) {
    float* sums = sumsA + (size_t)l * 2 * D;
    if (l == 0)
      k_agg<0><<<(N + 3) / 4, 256, 0, stream>>>(cmb, scid, offs, nullptr, nullptr, cid, aggbf, N);
    else
      k_agg<1><<<(N + 3) / 4, 256, 0, stream>>>(hb, ssrc, offs, scale, scale + D, nullptr, aggbf, N);
    k_gemm<K1P, 1><<<5 * RT, 256, 0, stream>>>(
        aggbf, W1tA + (size_t)l * W1ROWS * K1P, b1 + (size_t)l * H1, hid, nullptr, N, H1, H1P, 5);
    k_gemm<H1P, 0><<<3 * RT, 256, 0, stream>>>(
        hid, W2tA + (size_t)l * W2ROWS * H1P, b2 + (size_t)l * D, hb, sums, N, D, K1P, 3);
    k_bnfinal<<<1, 320, 0, stream>>>(sums, sums + D, gamma + (size_t)l * D, beta + (size_t)l * D,
                                     scale, scale + D, N);
  }

  float* out = (float*)d_out;
  float* out_pooled = out;
  float* out_nf = out + (size_t)B * D;
  float* out_mask = out + (size_t)B * D + (size_t)B * MAXLEN * D;
  k_pool<<<(B * 75 + 255) / 256, 256, 0, stream>>>(hb, scale, scale + D, gs, gc, out_pooled, B * 75);
  k_nf<<<B, 256, 0, stream>>>(hb, scale, scale + D, gs, gc, out_nf, out_mask);
}

// Round 17
// 1678.394 us; speedup vs baseline: 1.1453x; 1.1453x over previous
//
#include <hip/hip_runtime.h>
#include <cstdint>

#define D 300
#define MAXLEN 50
#define K1P 320    // bf16 row stride for aggbf/hb/cmb (640B); gemm1 K. cols 300-317 = combo counts
#define H1 600     // hidden dim
#define H1P 608    // hid bf16 row stride (1216B); gemm2 K
#define W1ROWS 640 // padded rows for W1t (5 col-tiles of 128)
#define W2ROWS 384 // padded rows for W2t (3 col-tiles of 128)

typedef __attribute__((ext_vector_type(8))) short s16x8;
typedef __attribute__((ext_vector_type(4))) short s16x4;
typedef __attribute__((ext_vector_type(4))) float f32x4;
typedef __attribute__((ext_vector_type(2))) float f32x2;
typedef __attribute__((ext_vector_type(4))) int i32x4;

__device__ __forceinline__ unsigned short f2b(float f) {
  uint32_t u = __builtin_bit_cast(uint32_t, f);
  u += 0x7FFFu + ((u >> 16) & 1u);
  return (unsigned short)(u >> 16);
}
__device__ __forceinline__ float b2f(unsigned short s) {
  return __builtin_bit_cast(float, (uint32_t)s << 16);
}
__device__ __forceinline__ void gld_lds16(const void* g, void* l) {
  __builtin_amdgcn_global_load_lds((const __attribute__((address_space(1))) void*)g,
                                   (__attribute__((address_space(3))) void*)l, 16, 0, 0);
}

// ---------------- combo embedding table: cmb[a*3+b] = xe1[a] + xe2[b] ----------------
__global__ void k_cmb(const float* __restrict__ xe1, const float* __restrict__ xe2,
                      unsigned short* __restrict__ cmb, int total /* 360*75 */) {
  int i = blockIdx.x * blockDim.x + threadIdx.x;
  if (i >= total) return;
  int c = i / 75, d = (i - c * 75) * 4;
  int a = c / 3, b = c - a * 3;
  s16x4 out;
#pragma unroll
  for (int j = 0; j < 4; ++j) out[j] = (short)f2b(xe1[(size_t)a * D + d + j] + xe2[(size_t)b * D + d + j]);
  *(s16x4*)(cmb + (size_t)c * K1P + d) = out;
}

// per-node combo id
__global__ void k_cid(const int* __restrict__ x, int* __restrict__ cid, int N) {
  int i = blockIdx.x * blockDim.x + threadIdx.x;
  if (i < N) cid[i] = x[2 * i] * 3 + x[2 * i + 1];
}

__global__ void k_count(const int* __restrict__ key, int* __restrict__ cnt, int n) {
  int i = blockIdx.x * blockDim.x + threadIdx.x;
  if (i < n) atomicAdd(&cnt[key[i]], 1);
}

// ---------------- hierarchical exclusive scan (1024 elems/block) ----------------
__global__ void k_scan1(const int* __restrict__ in, int* __restrict__ part, int n) {
  __shared__ int red[256];
  int tid = threadIdx.x;
  int base = blockIdx.x * 1024 + tid * 4;
  i32x4 v = {0, 0, 0, 0};
  if (base + 3 < n) v = *(const i32x4*)(in + base);
  else {
#pragma unroll
    for (int k = 0; k < 4; ++k) v[k] = (base + k < n) ? in[base + k] : 0;
  }
  int s = v[0] + v[1] + v[2] + v[3];
  red[tid] = s;
  __syncthreads();
  for (int off = 1; off < 256; off <<= 1) {
    int t = (tid >= off) ? red[tid - off] : 0;
    __syncthreads();
    red[tid] += t;
    __syncthreads();
  }
  if (tid == 255) part[blockIdx.x] = red[255];
}

__global__ void k_scan2(int* __restrict__ part, int P) {
  __shared__ int sm[1024];
  int tid = threadIdx.x;
  int v = (tid < P) ? part[tid] : 0;
  sm[tid] = v;
  __syncthreads();
  for (int off = 1; off < 1024; off <<= 1) {
    int t = (tid >= off) ? sm[tid - off] : 0;
    __syncthreads();
    sm[tid] += t;
    __syncthreads();
  }
  if (tid < P) part[tid] = sm[tid] - v;
  if (tid == 1023) part[P] = sm[1023];
}

__global__ void k_scan3(const int* __restrict__ in, const int* __restrict__ part,
                        int* __restrict__ out, int n, int P) {
  __shared__ int red[256];
  int tid = threadIdx.x;
  int base = blockIdx.x * 1024 + tid * 4;
  i32x4 v = {0, 0, 0, 0};
  if (base + 3 < n) v = *(const i32x4*)(in + base);
  else {
#pragma unroll
    for (int k = 0; k < 4; ++k) v[k] = (base + k < n) ? in[base + k] : 0;
  }
  int s = v[0] + v[1] + v[2] + v[3];
  red[tid] = s;
  __syncthreads();
  for (int off = 1; off < 256; off <<= 1) {
    int t = (tid >= off) ? red[tid - off] : 0;
    __syncthreads();
    red[tid] += t;
    __syncthreads();
  }
  int pre = red[tid] - s + part[blockIdx.x];
  if (base < n) out[base] = pre;
  if (base + 1 < n) out[base + 1] = pre + v[0];
  if (base + 2 < n) out[base + 2] = pre + v[0] + v[1];
  if (base + 3 < n) out[base + 3] = pre + v[0] + v[1] + v[2];
  if (blockIdx.x == 0 && tid == 0) out[n] = part[P];
}

// dst-sorted node ids (ssrc), layer0 row ids (scid); per-dst combo histogram (cnt18)
__global__ void k_fill(const int* __restrict__ src, const int* __restrict__ dst,
                       const int* __restrict__ ea, const int* __restrict__ cid,
                       int* __restrict__ cur, const int* __restrict__ offs,
                       int* __restrict__ ssrc, int* __restrict__ scid,
                       int* __restrict__ cnt18, int E_) {
  int e = blockIdx.x * blockDim.x + threadIdx.x;
  if (e >= E_) return;
  int d = dst[e];
  int s = src[e];
  int p = atomicAdd(&cur[d], 1);
  int pos = offs[d] + p;
  ssrc[pos] = s;
  scid[pos] = cid[s];
  int co = ea[2 * e] * 3 + ea[2 * e + 1];
  atomicAdd(&cnt18[d * 18 + co], 1);
}

// write combo counts (bf16) into aggbf cols 300..317 (+1 on combo 12 = self loop); zero 318/319
__global__ void k_cnt18bf(const int* __restrict__ cnt18, unsigned short* __restrict__ aggbf, int N) {
  int idx = blockIdx.x * blockDim.x + threadIdx.x;
  if (idx >= N * 10) return;
  int i = idx / 10, j = idx - i * 10;
  uint32_t o = 0;
  if (j < 9) {
    int c0 = cnt18[i * 18 + 2 * j] + (2 * j == 12 ? 1 : 0);
    int c1 = cnt18[i * 18 + 2 * j + 1];
    o = (uint32_t)f2b((float)c0) | ((uint32_t)f2b((float)c1) << 16);
  }
  *(uint32_t*)(aggbf + (size_t)i * K1P + D + j * 2) = o;
}

// ecW1 rows of W1t: W1t[n][300+k18] = bf16( sum_d (ee1[l][k18/3][d]+ee2[l][k18%3][d]) * W1[l][d][n] )
__global__ void k_ecw1(const float* __restrict__ ee1, const float* __restrict__ ee2,
                       const float* __restrict__ W1, unsigned short* __restrict__ W1tA,
                       int L_, int total /* L*600*18 */) {
  int idx = blockIdx.x * blockDim.x + threadIdx.x;
  if (idx >= total) return;
  int k18 = idx % 18;
  int n = (idx / 18) % H1;
  int l = idx / (18 * H1);
  const float* e1 = ee1 + ((size_t)l * 6 + k18 / 3) * D;
  const float* e2 = ee2 + ((size_t)l * 3 + k18 % 3) * D;
  const float* w = W1 + (size_t)l * D * H1 + n;
  float s = 0.f;
  for (int d = 0; d < D; ++d) s += (e1[d] + e2[d]) * w[(size_t)d * H1];
  W1tA[(size_t)l * W1ROWS * K1P + (size_t)n * K1P + D + k18] = f2b(s);
}

// ---------------- aggregation: one wave per node; pure h-gathers (ec via counts@ecW1) ----------------
template <int FUSE>
__global__ void k_agg(const unsigned short* __restrict__ hin, const int* __restrict__ ridx,
                      const int* __restrict__ offs, const float* __restrict__ scale,
                      const float* __restrict__ shift, const int* __restrict__ selfcid,
                      unsigned short* __restrict__ aggbf, int N) {
  int w = (int)((blockIdx.x * blockDim.x + threadIdx.x) >> 6);
  if (w >= N) return;
  int lane = threadIdx.x & 63;
  float sc0[3], sc1[3], sh0[3], sh1[3];
#pragma unroll
  for (int i = 0; i < 3; ++i) {
    int d2 = i * 64 + lane;
    if (FUSE && d2 < 150) {
      f32x2 s = *(const f32x2*)(scale + d2 * 2);
      f32x2 t = *(const f32x2*)(shift + d2 * 2);
      sc0[i] = s[0]; sc1[i] = s[1]; sh0[i] = t[0]; sh1[i] = t[1];
    } else { sc0[i] = sc1[i] = sh0[i] = sh1[i] = 0.f; }
  }
  int beg = offs[w], end = offs[w + 1];
  int wrow = FUSE ? w : selfcid[w];
  float s0[3], s1[3];
#pragma unroll
  for (int i = 0; i < 3; ++i) {
    int d2 = i * 64 + lane;
    float a = 0.f, b = 0.f;
    if (d2 < 150) {
      uint32_t u = *(const uint32_t*)(hin + (size_t)wrow * K1P + d2 * 2);
      a = b2f((unsigned short)(u & 0xFFFF));
      b = b2f((unsigned short)(u >> 16));
      if (FUSE) { a = fmaxf(a * sc0[i] + sh0[i], 0.f); b = fmaxf(b * sc1[i] + sh1[i], 0.f); }
    }
    s0[i] = a; s1[i] = b;
  }
  int j = beg;
  for (; j + 4 <= end; j += 4) {
    int sv0 = ridx[j], sv1 = ridx[j + 1], sv2 = ridx[j + 2], sv3 = ridx[j + 3];
    const unsigned short* p0 = hin + (size_t)sv0 * K1P;
    const unsigned short* p1 = hin + (size_t)sv1 * K1P;
    const unsigned short* p2 = hin + (size_t)sv2 * K1P;
    const unsigned short* p3 = hin + (size_t)sv3 * K1P;
#pragma unroll
    for (int i = 0; i < 3; ++i) {
      int d2 = i * 64 + lane;
      if (d2 < 150) {
        uint32_t u0 = *(const uint32_t*)(p0 + d2 * 2);
        uint32_t u1 = *(const uint32_t*)(p1 + d2 * 2);
        uint32_t u2 = *(const uint32_t*)(p2 + d2 * 2);
        uint32_t u3 = *(const uint32_t*)(p3 + d2 * 2);
        float a0 = b2f((unsigned short)(u0 & 0xFFFF)), b0 = b2f((unsigned short)(u0 >> 16));
        float a1 = b2f((unsigned short)(u1 & 0xFFFF)), b1 = b2f((unsigned short)(u1 >> 16));
        float a2 = b2f((unsigned short)(u2 & 0xFFFF)), b2 = b2f((unsigned short)(u2 >> 16));
        float a3 = b2f((unsigned short)(u3 & 0xFFFF)), b3 = b2f((unsigned short)(u3 >> 16));
        if (FUSE) {
          a0 = fmaxf(a0 * sc0[i] + sh0[i], 0.f); b0 = fmaxf(b0 * sc1[i] + sh1[i], 0.f);
          a1 = fmaxf(a1 * sc0[i] + sh0[i], 0.f); b1 = fmaxf(b1 * sc1[i] + sh1[i], 0.f);
          a2 = fmaxf(a2 * sc0[i] + sh0[i], 0.f); b2 = fmaxf(b2 * sc1[i] + sh1[i], 0.f);
          a3 = fmaxf(a3 * sc0[i] + sh0[i], 0.f); b3 = fmaxf(b3 * sc1[i] + sh1[i], 0.f);
        }
        s0[i] += (a0 + a1) + (a2 + a3);
        s1[i] += (b0 + b1) + (b2 + b3);
      }
    }
  }
  for (; j < end; ++j) {
    int sv = ridx[j];
    const unsigned short* rp = hin + (size_t)sv * K1P;
#pragma unroll
    for (int i = 0; i < 3; ++i) {
      int d2 = i * 64 + lane;
      if (d2 < 150) {
        uint32_t u = *(const uint32_t*)(rp + d2 * 2);
        float a = b2f((unsigned short)(u & 0xFFFF)), b = b2f((unsigned short)(u >> 16));
        if (FUSE) { a = fmaxf(a * sc0[i] + sh0[i], 0.f); b = fmaxf(b * sc1[i] + sh1[i], 0.f); }
        s0[i] += a;
        s1[i] += b;
      }
    }
  }
#pragma unroll
  for (int i = 0; i < 3; ++i) {
    int d2 = i * 64 + lane;
    if (d2 < 150) {
      uint32_t o = (uint32_t)f2b(s0[i]) | ((uint32_t)f2b(s1[i]) << 16);
      *(uint32_t*)(aggbf + (size_t)w * K1P + d2 * 2) = o;
    }
  }
}

// transpose+convert weights: Wt[n][k] = bf16(W[k][n]), zero-padded
__global__ void k_wconv(const float* __restrict__ W, unsigned short* __restrict__ Wt,
                        int K, int Nout, int Kp, int total) {
  int idx = blockIdx.x * blockDim.x + threadIdx.x;
  if (idx >= total) return;
  int n = idx / Kp, k = idx - n * Kp;
  float v = (k < K && n < Nout) ? W[(size_t)k * Nout + n] : 0.f;
  Wt[idx] = f2b(v);
}

// ---------------- 3-buffer counted-vmcnt MFMA GEMM (R10/R13-measured-good, final) ----------------
// Session record: R8 (swapped-operand epilogue), R11 (4-buffer), R12 (BN-inline),
// R14/R16 (reg-A; VGPR spills both times) all regressed vs this version. It is the
// measured local optimum of this structure (~140us/gemm1, MfmaUtil ~13.5%). The
// remaining gap to roofline requires the 256^2 8-phase template (ground-up rewrite).
template <int K, int EPI>
__global__ __launch_bounds__(256, 3) void k_gemm(
    const unsigned short* __restrict__ A, const unsigned short* __restrict__ Bt,
    const float* __restrict__ bias, unsigned short* __restrict__ Cb,
    float* __restrict__ sums, int M, int Nout, int ldc, int CT) {
  constexpr int T = K / 32;
  __shared__ __align__(16) unsigned short smem[24576];  // 3 x (A 4096 | B 4096) shorts = 48 KB

  int nwg = gridDim.x;
  int q = nwg >> 3, r8 = nwg & 7;
  int xcd = blockIdx.x & 7, oidx = blockIdx.x >> 3;
  int wid = (xcd < r8 ? xcd * (q + 1) : r8 * (q + 1) + (xcd - r8) * q) + oidx;
  int ct = wid % CT, rt = wid / CT;
  const int rowBase = rt * 128, colBase = ct * 128;

  const int tid = threadIdx.x, lane = tid & 63, wave = tid >> 6;
  const int wm = wave >> 1, wn = wave & 1;
  const int l15 = lane & 15, lg = lane >> 4;

  unsigned short* Asm = smem;          // [3][128r][4 chunks][8]
  unsigned short* Bsm = smem + 12288;

  auto stage = [&](int s, int t) {
#pragma unroll
    for (int i = 0; i < 2; ++i) {
      int u = tid + i * 256;
      int rr = u >> 2;
      int cdat = (u & 3) ^ ((rr >> 1) & 3);  // inverse-swizzled source chunk
      int gr = rowBase + rr; if (gr >= M) gr = M - 1;
      gld_lds16(A + (size_t)gr * K + t * 32 + cdat * 8, Asm + s * 4096 + u * 8);
      gld_lds16(Bt + (size_t)(colBase + rr) * K + t * 32 + cdat * 8, Bsm + s * 4096 + u * 8);
    }
  };

  f32x4 acc[4][4] = {};
  stage(0, 0);
  stage(1, 1);
#pragma unroll
  for (int t = 0; t < T; ++t) {
    if (t + 1 < T) asm volatile("s_waitcnt vmcnt(4)" ::: "memory");
    else           asm volatile("s_waitcnt vmcnt(0)" ::: "memory");
    __builtin_amdgcn_s_barrier();
    __builtin_amdgcn_sched_barrier(0);
    const unsigned short* bA = Asm + (t % 3) * 4096;
    const unsigned short* bB = Bsm + (t % 3) * 4096;
    s16x8 af[4], bf[4];
#pragma unroll
    for (int i = 0; i < 4; ++i) {
      int ra = wm * 64 + i * 16 + l15;
      int rb = wn * 64 + i * 16 + l15;
      af[i] = *(const s16x8*)(bA + ((size_t)ra * 4 + (lg ^ ((ra >> 1) & 3))) * 8);
      bf[i] = *(const s16x8*)(bB + ((size_t)rb * 4 + (lg ^ ((rb >> 1) & 3))) * 8);
    }
    if (t + 2 < T) stage((t + 2) % 3, t + 2);
#pragma unroll
    for (int mi = 0; mi < 4; ++mi)
#pragma unroll
      for (int ni = 0; ni < 4; ++ni)
        acc[mi][ni] = __builtin_amdgcn_mfma_f32_16x16x32_bf16(af[mi], bf[ni], acc[mi][ni], 0, 0, 0);
  }

  // epilogue: direct u16 stores
  float bnS[4] = {0.f, 0.f, 0.f, 0.f}, bnQ[4] = {0.f, 0.f, 0.f, 0.f};
#pragma unroll
  for (int ni = 0; ni < 4; ++ni) {
    int col = colBase + wn * 64 + ni * 16 + l15;
    if (col >= (EPI ? ldc : Nout)) continue;  // gemm2: skip dead pad cols
    bool inN = col < Nout;
    float bv = inN ? bias[col] : 0.f;
#pragma unroll
    for (int mi = 0; mi < 4; ++mi) {
      int row0 = rowBase + wm * 64 + mi * 16 + lg * 4;
#pragma unroll
      for (int rr = 0; rr < 4; ++rr) {
        int row = row0 + rr;
        if (row < M) {
          float v = inN ? acc[mi][ni][rr] + bv : 0.f;
          if (EPI) v = fmaxf(v, 0.f);
          else { bnS[ni] += v; bnQ[ni] += v * v; }
          Cb[(size_t)row * ldc + col] = f2b(v);
        }
      }
    }
  }
  if (!EPI) {
#pragma unroll
    for (int ni = 0; ni < 4; ++ni) {
      float cs = bnS[ni], cq = bnQ[ni];
      cs += __shfl_xor(cs, 16); cq += __shfl_xor(cq, 16);
      cs += __shfl_xor(cs, 32); cq += __shfl_xor(cq, 32);
      int col = colBase + wn * 64 + ni * 16 + l15;
      if (lg == 0 && col < Nout) {
        atomicAdd(&sums[col], cs);
        atomicAdd(&sums[D + col], cq);
      }
    }
  }
}

// ---------------- BatchNorm finalize ----------------
__global__ void k_bnfinal(const float* __restrict__ sums, const float* __restrict__ sumsq,
                          const float* __restrict__ gamma, const float* __restrict__ beta,
                          float* __restrict__ scale, float* __restrict__ shift, int N) {
  int c = threadIdx.x;
  if (c >= D) return;
  float inv = 1.f / (float)N;
  float mean = sums[c] * inv;
  float var = sumsq[c] * inv - mean * mean;
  if (var < 0.f) var = 0.f;
  float sc = gamma[c] * rsqrtf(var + 1e-5f);
  scale[c] = sc;
  shift[c] = beta[c] - mean * sc;
}

// ---------------- outputs (BN of last layer fused; no relu), vectorized ----------------
__global__ void k_pool(const unsigned short* __restrict__ hb, const float* __restrict__ scale,
                       const float* __restrict__ shift, const int* __restrict__ gs,
                       const int* __restrict__ gc, float* __restrict__ pooled, int total /* B*75 */) {
  int gid = blockIdx.x * blockDim.x + threadIdx.x;
  if (gid >= total) return;
  int g = gid / 75, c4 = (gid - g * 75) * 4;
  int start = gs[g], cnt = gc[g];
  f32x4 s = {0.f, 0.f, 0.f, 0.f};
  for (int i = 0; i < cnt; ++i) {
    s16x4 in = *(const s16x4*)(hb + (size_t)(start + i) * K1P + c4);
#pragma unroll
    for (int j = 0; j < 4; ++j) s[j] += b2f((unsigned short)in[j]);
  }
  f32x4 sc = *(const f32x4*)(scale + c4);
  f32x4 sh = *(const f32x4*)(shift + c4);
  float dv = (cnt > 0) ? (float)cnt : 1.f;
  f32x4 out;
#pragma unroll
  for (int j = 0; j < 4; ++j) out[j] = (s[j] * sc[j] + sh[j] * (float)cnt) / dv;
  *(f32x4*)(pooled + (size_t)g * D + c4) = out;
}

__global__ void k_nf(const unsigned short* __restrict__ hb, const float* __restrict__ scale,
                     const float* __restrict__ shift, const int* __restrict__ gs,
                     const int* __restrict__ gc, float* __restrict__ nf, float* __restrict__ mask) {
  int g = blockIdx.x;
  int start = gs[g], cnt = gc[g];
  int lim = cnt < MAXLEN ? cnt : MAXLEN;
  for (int idx = threadIdx.x; idx < MAXLEN * 75; idx += 256) {
    int p = idx / 75;
    int c4 = (idx - p * 75) * 4;
    f32x4 v = {0.f, 0.f, 0.f, 0.f};
    if (p < lim) {
      s16x4 in = *(const s16x4*)(hb + (size_t)(start + p) * K1P + c4);
      f32x4 sc = *(const f32x4*)(scale + c4);
      f32x4 sh = *(const f32x4*)(shift + c4);
#pragma unroll
      for (int j = 0; j < 4; ++j) v[j] = b2f((unsigned short)in[j]) * sc[j] + sh[j];
    }
    *(f32x4*)(nf + (size_t)g * (MAXLEN * D) + p * D + c4) = v;
  }
  if (threadIdx.x < MAXLEN) mask[(size_t)g * MAXLEN + threadIdx.x] = (threadIdx.x < lim) ? 1.f : 0.f;
}

extern "C" void kernel_launch(void* const* d_in, const int* in_sizes, int n_in,
                              void* d_out, int out_size, void* d_ws, size_t ws_size,
                              hipStream_t stream) {
  const int* x      = (const int*)d_in[0];
  const int* ei     = (const int*)d_in[1];   // [2][E]: src = ei, dst = ei+E
  const int* ea     = (const int*)d_in[2];   // [E][2]
  const int* batch  = (const int*)d_in[3];
  const float* xe1  = (const float*)d_in[5];
  const float* xe2  = (const float*)d_in[6];
  const float* ee1  = (const float*)d_in[7]; // [L][6][D]
  const float* ee2  = (const float*)d_in[8]; // [L][3][D]
  const float* W1   = (const float*)d_in[9];
  const float* b1   = (const float*)d_in[10];
  const float* W2   = (const float*)d_in[11];
  const float* b2   = (const float*)d_in[12];
  const float* gamma = (const float*)d_in[13];
  const float* beta  = (const float*)d_in[14];

  const int N = in_sizes[0] / 2;
  const int E = in_sizes[1] / 2;
  const int L = in_sizes[9] / (D * 2 * D);
  const int B = out_size / (D + MAXLEN * D + MAXLEN);

  char* ws = (char*)d_ws;
  size_t off = 0;
  auto alloc = [&](size_t bytes) -> void* {
    void* p = ws + off;
    off += (bytes + 255) & ~(size_t)255;
    return p;
  };
  unsigned short* aggbf = (unsigned short*)alloc((size_t)N * K1P * 2);
  unsigned short* hb    = (unsigned short*)alloc((size_t)N * K1P * 2);
  unsigned short* hid   = (unsigned short*)alloc((size_t)N * H1P * 2);
  unsigned short* cmb   = (unsigned short*)alloc((size_t)360 * K1P * 2);
  unsigned short* W1tA = (unsigned short*)alloc((size_t)L * W1ROWS * K1P * 2);
  unsigned short* W2tA = (unsigned short*)alloc((size_t)L * W2ROWS * H1P * 2);
  int* cnt    = (int*)alloc((size_t)N * 4);
  int* cur    = (int*)alloc((size_t)N * 4);
  int* offs   = (int*)alloc((size_t)(N + 1) * 4);
  int* cid    = (int*)alloc((size_t)N * 4);
  int* cnt18  = (int*)alloc((size_t)N * 18 * 4);
  int* ssrc   = (int*)alloc((size_t)E * 4);
  int* scid   = (int*)alloc((size_t)E * 4);
  int* gc     = (int*)alloc((size_t)B * 4);
  int* gs     = (int*)alloc((size_t)(B + 1) * 4);
  int* part   = (int*)alloc(1024 * 4);
  float* sumsA = (float*)alloc((size_t)L * 2 * D * 4);
  float* scale = (float*)alloc(2 * D * 4);  // scale | shift

  hipMemsetAsync(cnt, 0, (size_t)N * 4, stream);
  hipMemsetAsync(cur, 0, (size_t)N * 4, stream);
  hipMemsetAsync(gc, 0, (size_t)B * 4, stream);
  hipMemsetAsync(cnt18, 0, (size_t)N * 18 * 4, stream);
  hipMemsetAsync(sumsA, 0, (size_t)L * 2 * D * 4, stream);

  k_cmb<<<(360 * 75 + 255) / 256, 256, 0, stream>>>(xe1, xe2, cmb, 360 * 75);
  k_cid<<<(N + 255) / 256, 256, 0, stream>>>(x, cid, N);
  k_count<<<(E + 255) / 256, 256, 0, stream>>>(ei + E, cnt, E);
  {
    int P = (N + 1023) / 1024;
    k_scan1<<<P, 256, 0, stream>>>(cnt, part, N);
    k_scan2<<<1, 1024, 0, stream>>>(part, P);
    k_scan3<<<P, 256, 0, stream>>>(cnt, part, offs, N, P);
  }
  k_fill<<<(E + 255) / 256, 256, 0, stream>>>(ei, ei + E, ea, cid, cur, offs, ssrc, scid, cnt18, E);
  k_cnt18bf<<<(N * 10 + 255) / 256, 256, 0, stream>>>(cnt18, aggbf, N);
  k_count<<<(N + 255) / 256, 256, 0, stream>>>(batch, gc, N);
  {
    int P = (B + 1023) / 1024;
    k_scan1<<<P, 256, 0, stream>>>(gc, part, B);
    k_scan2<<<1, 1024, 0, stream>>>(part, P);
    k_scan3<<<P, 256, 0, stream>>>(gc, part, gs, B, P);
  }
  for (int l = 0; l < L; ++l) {
    k_wconv<<<(W1ROWS * K1P + 255) / 256, 256, 0, stream>>>(
        W1 + (size_t)l * D * H1, W1tA + (size_t)l * W1ROWS * K1P, D, H1, K1P, W1ROWS * K1P);
    k_wconv<<<(W2ROWS * H1P + 255) / 256, 256, 0, stream>>>(
        W2 + (size_t)l * H1 * D, W2tA + (size_t)l * W2ROWS * H1P, H1, D, H1P, W2ROWS * H1P);
  }
  k_ecw1<<<(L * H1 * 18 + 255) / 256, 256, 0, stream>>>(ee1, ee2, W1, W1tA, L, L * H1 * 18);

  const int RT = (N + 127) / 128;
  for (int l = 0; l < L; ++l) {
    float* sums = sumsA + (size_t)l * 2 * D;
    if (l == 0)
      k_agg<0><<<(N + 3) / 4, 256, 0, stream>>>(cmb, scid, offs, nullptr, nullptr, cid, aggbf, N);
    else
      k_agg<1><<<(N + 3) / 4, 256, 0, stream>>>(hb, ssrc, offs, scale, scale + D, nullptr, aggbf, N);
    k_gemm<K1P, 1><<<5 * RT, 256, 0, stream>>>(
        aggbf, W1tA + (size_t)l * W1ROWS * K1P, b1 + (size_t)l * H1, hid, nullptr, N, H1, H1P, 5);
    k_gemm<H1P, 0><<<3 * RT, 256, 0, stream>>>(
        hid, W2tA + (size_t)l * W2ROWS * H1P, b2 + (size_t)l * D, hb, sums, N, D, K1P, 3);
    k_bnfinal<<<1, 320, 0, stream>>>(sums, sums + D, gamma + (size_t)l * D, beta + (size_t)l * D,
                                     scale, scale + D, N);
  }

  float* out = (float*)d_out;
  float* out_pooled = out;
  float* out_nf = out + (size_t)B * D;
  float* out_mask = out + (size_t)B * D + (size_t)B * MAXLEN * D;
  k_pool<<<(B * 75 + 255) / 256, 256, 0, stream>>>(hb, scale, scale + D, gs, gc, out_pooled, B * 75);
  k_nf<<<B, 256, 0, stream>>>(hb, scale, scale + D, gs, gc, out_nf, out_mask);
}

// Round 18
// 1464.195 us; speedup vs baseline: 1.3128x; 1.1463x over previous
//
#include <hip/hip_runtime.h>
#include <cstdint>

#define D 300
#define MAXLEN 50
#define K1P 320    // bf16 row stride for aggbf/hb/cmb (640B); gemm1 K. cols 300-317 = combo counts
#define H1 600     // hidden dim
#define H1P 608    // hid bf16 row stride (1216B); gemm2 K
#define W1ROWS 640 // padded rows for W1t (5 col-tiles of 128)
#define W2ROWS 384 // padded rows for W2t (3 col-tiles of 128)

typedef __attribute__((ext_vector_type(8))) short s16x8;
typedef __attribute__((ext_vector_type(4))) short s16x4;
typedef __attribute__((ext_vector_type(4))) float f32x4;
typedef __attribute__((ext_vector_type(2))) float f32x2;
typedef __attribute__((ext_vector_type(4))) int i32x4;

__device__ __forceinline__ unsigned short f2b(float f) {
  uint32_t u = __builtin_bit_cast(uint32_t, f);
  u += 0x7FFFu + ((u >> 16) & 1u);
  return (unsigned short)(u >> 16);
}
__device__ __forceinline__ float b2f(unsigned short s) {
  return __builtin_bit_cast(float, (uint32_t)s << 16);
}
__device__ __forceinline__ void gld_lds16(const void* g, void* l) {
  __builtin_amdgcn_global_load_lds((const __attribute__((address_space(1))) void*)g,
                                   (__attribute__((address_space(3))) void*)l, 16, 0, 0);
}

// ---------------- combo embedding table: cmb[a*3+b] = xe1[a] + xe2[b] ----------------
__global__ void k_cmb(const float* __restrict__ xe1, const float* __restrict__ xe2,
                      unsigned short* __restrict__ cmb, int total /* 360*75 */) {
  int i = blockIdx.x * blockDim.x + threadIdx.x;
  if (i >= total) return;
  int c = i / 75, d = (i - c * 75) * 4;
  int a = c / 3, b = c - a * 3;
  s16x4 out;
#pragma unroll
  for (int j = 0; j < 4; ++j) out[j] = (short)f2b(xe1[(size_t)a * D + d + j] + xe2[(size_t)b * D + d + j]);
  *(s16x4*)(cmb + (size_t)c * K1P + d) = out;
}

// per-node combo id
__global__ void k_cid(const int* __restrict__ x, int* __restrict__ cid, int N) {
  int i = blockIdx.x * blockDim.x + threadIdx.x;
  if (i < N) cid[i] = x[2 * i] * 3 + x[2 * i + 1];
}

__global__ void k_count(const int* __restrict__ key, int* __restrict__ cnt, int n) {
  int i = blockIdx.x * blockDim.x + threadIdx.x;
  if (i < n) atomicAdd(&cnt[key[i]], 1);
}

// ---------------- hierarchical exclusive scan (1024 elems/block) ----------------
__global__ void k_scan1(const int* __restrict__ in, int* __restrict__ part, int n) {
  __shared__ int red[256];
  int tid = threadIdx.x;
  int base = blockIdx.x * 1024 + tid * 4;
  i32x4 v = {0, 0, 0, 0};
  if (base + 3 < n) v = *(const i32x4*)(in + base);
  else {
#pragma unroll
    for (int k = 0; k < 4; ++k) v[k] = (base + k < n) ? in[base + k] : 0;
  }
  int s = v[0] + v[1] + v[2] + v[3];
  red[tid] = s;
  __syncthreads();
  for (int off = 1; off < 256; off <<= 1) {
    int t = (tid >= off) ? red[tid - off] : 0;
    __syncthreads();
    red[tid] += t;
    __syncthreads();
  }
  if (tid == 255) part[blockIdx.x] = red[255];
}

__global__ void k_scan2(int* __restrict__ part, int P) {
  __shared__ int sm[1024];
  int tid = threadIdx.x;
  int v = (tid < P) ? part[tid] : 0;
  sm[tid] = v;
  __syncthreads();
  for (int off = 1; off < 1024; off <<= 1) {
    int t = (tid >= off) ? sm[tid - off] : 0;
    __syncthreads();
    sm[tid] += t;
    __syncthreads();
  }
  if (tid < P) part[tid] = sm[tid] - v;
  if (tid == 1023) part[P] = sm[1023];
}

__global__ void k_scan3(const int* __restrict__ in, const int* __restrict__ part,
                        int* __restrict__ out, int n, int P) {
  __shared__ int red[256];
  int tid = threadIdx.x;
  int base = blockIdx.x * 1024 + tid * 4;
  i32x4 v = {0, 0, 0, 0};
  if (base + 3 < n) v = *(const i32x4*)(in + base);
  else {
#pragma unroll
    for (int k = 0; k < 4; ++k) v[k] = (base + k < n) ? in[base + k] : 0;
  }
  int s = v[0] + v[1] + v[2] + v[3];
  red[tid] = s;
  __syncthreads();
  for (int off = 1; off < 256; off <<= 1) {
    int t = (tid >= off) ? red[tid - off] : 0;
    __syncthreads();
    red[tid] += t;
    __syncthreads();
  }
  int pre = red[tid] - s + part[blockIdx.x];
  if (base < n) out[base] = pre;
  if (base + 1 < n) out[base + 1] = pre + v[0];
  if (base + 2 < n) out[base + 2] = pre + v[0] + v[1];
  if (base + 3 < n) out[base + 3] = pre + v[0] + v[1] + v[2];
  if (blockIdx.x == 0 && tid == 0) out[n] = part[P];
}

// dst-sorted node ids (ssrc), layer0 row ids (scid); per-dst combo histogram (cnt18)
__global__ void k_fill(const int* __restrict__ src, const int* __restrict__ dst,
                       const int* __restrict__ ea, const int* __restrict__ cid,
                       int* __restrict__ cur, const int* __restrict__ offs,
                       int* __restrict__ ssrc, int* __restrict__ scid,
                       int* __restrict__ cnt18, int E_) {
  int e = blockIdx.x * blockDim.x + threadIdx.x;
  if (e >= E_) return;
  int d = dst[e];
  int s = src[e];
  int p = atomicAdd(&cur[d], 1);
  int pos = offs[d] + p;
  ssrc[pos] = s;
  scid[pos] = cid[s];
  int co = ea[2 * e] * 3 + ea[2 * e + 1];
  atomicAdd(&cnt18[d * 18 + co], 1);
}

// write combo counts (bf16) into aggbf cols 300..317 (+1 on combo 12 = self loop); zero 318/319
__global__ void k_cnt18bf(const int* __restrict__ cnt18, unsigned short* __restrict__ aggbf, int N) {
  int idx = blockIdx.x * blockDim.x + threadIdx.x;
  if (idx >= N * 10) return;
  int i = idx / 10, j = idx - i * 10;
  uint32_t o = 0;
  if (j < 9) {
    int c0 = cnt18[i * 18 + 2 * j] + (2 * j == 12 ? 1 : 0);
    int c1 = cnt18[i * 18 + 2 * j + 1];
    o = (uint32_t)f2b((float)c0) | ((uint32_t)f2b((float)c1) << 16);
  }
  *(uint32_t*)(aggbf + (size_t)i * K1P + D + j * 2) = o;
}

// ecW1 rows of W1t: W1t[n][300+k18] = bf16( sum_d (ee1[l][k18/3][d]+ee2[l][k18%3][d]) * W1[l][d][n] )
__global__ void k_ecw1(const float* __restrict__ ee1, const float* __restrict__ ee2,
                       const float* __restrict__ W1, unsigned short* __restrict__ W1tA,
                       int L_, int total /* L*600*18 */) {
  int idx = blockIdx.x * blockDim.x + threadIdx.x;
  if (idx >= total) return;
  int k18 = idx % 18;
  int n = (idx / 18) % H1;
  int l = idx / (18 * H1);
  const float* e1 = ee1 + ((size_t)l * 6 + k18 / 3) * D;
  const float* e2 = ee2 + ((size_t)l * 3 + k18 % 3) * D;
  const float* w = W1 + (size_t)l * D * H1 + n;
  float s = 0.f;
  for (int d = 0; d < D; ++d) s += (e1[d] + e2[d]) * w[(size_t)d * H1];
  W1tA[(size_t)l * W1ROWS * K1P + (size_t)n * K1P + D + k18] = f2b(s);
}

// ---------------- aggregation: one wave per node; pure h-gathers (ec via counts@ecW1) ----------------
template <int FUSE>
__global__ void k_agg(const unsigned short* __restrict__ hin, const int* __restrict__ ridx,
                      const int* __restrict__ offs, const float* __restrict__ scale,
                      const float* __restrict__ shift, const int* __restrict__ selfcid,
                      unsigned short* __restrict__ aggbf, int N) {
  int w = (int)((blockIdx.x * blockDim.x + threadIdx.x) >> 6);
  if (w >= N) return;
  int lane = threadIdx.x & 63;
  float sc0[3], sc1[3], sh0[3], sh1[3];
#pragma unroll
  for (int i = 0; i < 3; ++i) {
    int d2 = i * 64 + lane;
    if (FUSE && d2 < 150) {
      f32x2 s = *(const f32x2*)(scale + d2 * 2);
      f32x2 t = *(const f32x2*)(shift + d2 * 2);
      sc0[i] = s[0]; sc1[i] = s[1]; sh0[i] = t[0]; sh1[i] = t[1];
    } else { sc0[i] = sc1[i] = sh0[i] = sh1[i] = 0.f; }
  }
  int beg = offs[w], end = offs[w + 1];
  int wrow = FUSE ? w : selfcid[w];
  float s0[3], s1[3];
#pragma unroll
  for (int i = 0; i < 3; ++i) {
    int d2 = i * 64 + lane;
    float a = 0.f, b = 0.f;
    if (d2 < 150) {
      uint32_t u = *(const uint32_t*)(hin + (size_t)wrow * K1P + d2 * 2);
      a = b2f((unsigned short)(u & 0xFFFF));
      b = b2f((unsigned short)(u >> 16));
      if (FUSE) { a = fmaxf(a * sc0[i] + sh0[i], 0.f); b = fmaxf(b * sc1[i] + sh1[i], 0.f); }
    }
    s0[i] = a; s1[i] = b;
  }
  int j = beg;
  for (; j + 4 <= end; j += 4) {
    int sv0 = ridx[j], sv1 = ridx[j + 1], sv2 = ridx[j + 2], sv3 = ridx[j + 3];
    const unsigned short* p0 = hin + (size_t)sv0 * K1P;
    const unsigned short* p1 = hin + (size_t)sv1 * K1P;
    const unsigned short* p2 = hin + (size_t)sv2 * K1P;
    const unsigned short* p3 = hin + (size_t)sv3 * K1P;
#pragma unroll
    for (int i = 0; i < 3; ++i) {
      int d2 = i * 64 + lane;
      if (d2 < 150) {
        uint32_t u0 = *(const uint32_t*)(p0 + d2 * 2);
        uint32_t u1 = *(const uint32_t*)(p1 + d2 * 2);
        uint32_t u2 = *(const uint32_t*)(p2 + d2 * 2);
        uint32_t u3 = *(const uint32_t*)(p3 + d2 * 2);
        float a0 = b2f((unsigned short)(u0 & 0xFFFF)), b0 = b2f((unsigned short)(u0 >> 16));
        float a1 = b2f((unsigned short)(u1 & 0xFFFF)), b1 = b2f((unsigned short)(u1 >> 16));
        float a2 = b2f((unsigned short)(u2 & 0xFFFF)), b2 = b2f((unsigned short)(u2 >> 16));
        float a3 = b2f((unsigned short)(u3 & 0xFFFF)), b3 = b2f((unsigned short)(u3 >> 16));
        if (FUSE) {
          a0 = fmaxf(a0 * sc0[i] + sh0[i], 0.f); b0 = fmaxf(b0 * sc1[i] + sh1[i], 0.f);
          a1 = fmaxf(a1 * sc0[i] + sh0[i], 0.f); b1 = fmaxf(b1 * sc1[i] + sh1[i], 0.f);
          a2 = fmaxf(a2 * sc0[i] + sh0[i], 0.f); b2 = fmaxf(b2 * sc1[i] + sh1[i], 0.f);
          a3 = fmaxf(a3 * sc0[i] + sh0[i], 0.f); b3 = fmaxf(b3 * sc1[i] + sh1[i], 0.f);
        }
        s0[i] += (a0 + a1) + (a2 + a3);
        s1[i] += (b0 + b1) + (b2 + b3);
      }
    }
  }
  for (; j < end; ++j) {
    int sv = ridx[j];
    const unsigned short* rp = hin + (size_t)sv * K1P;
#pragma unroll
    for (int i = 0; i < 3; ++i) {
      int d2 = i * 64 + lane;
      if (d2 < 150) {
        uint32_t u = *(const uint32_t*)(rp + d2 * 2);
        float a = b2f((unsigned short)(u & 0xFFFF)), b = b2f((unsigned short)(u >> 16));
        if (FUSE) { a = fmaxf(a * sc0[i] + sh0[i], 0.f); b = fmaxf(b * sc1[i] + sh1[i], 0.f); }
        s0[i] += a;
        s1[i] += b;
      }
    }
  }
#pragma unroll
  for (int i = 0; i < 3; ++i) {
    int d2 = i * 64 + lane;
    if (d2 < 150) {
      uint32_t o = (uint32_t)f2b(s0[i]) | ((uint32_t)f2b(s1[i]) << 16);
      *(uint32_t*)(aggbf + (size_t)w * K1P + d2 * 2) = o;
    }
  }
}

// transpose+convert weights: Wt[n][k] = bf16(W[k][n]), zero-padded
__global__ void k_wconv(const float* __restrict__ W, unsigned short* __restrict__ Wt,
                        int K, int Nout, int Kp, int total) {
  int idx = blockIdx.x * blockDim.x + threadIdx.x;
  if (idx >= total) return;
  int n = idx / Kp, k = idx - n * Kp;
  float v = (k < K && n < Nout) ? W[(size_t)k * Nout + n] : 0.f;
  Wt[idx] = f2b(v);
}

// ---------------- 8-wave 3-buffer counted-vmcnt MFMA GEMM (R18) ----------------
// Same 128x128 tile, same proven 3-buffer schedule/swizzle as R13; only the thread
// geometry changes: 512 threads = 8 waves (2 M-halves x 4 N-quarters, each wave
// 64x32, acc[4][2] = 32 VGPR). LDS unchanged 48 KB -> still 3 blocks/CU, but
// 24 waves/CU (was 12): 2x TLP against the diagnosed latency bound. Staging:
// 512 thr x 16B = one 8KB tile per issue -> 1 A + 1 B gld_lds per thread per step;
// FIFO gives vmcnt(2) steady (S(t+1) in flight), vmcnt(0) tail.
// launch_bounds(512,4): VGPR cap 128 >> ~85 design (no R14/R16 spill mode).
template <int K, int EPI>
__global__ __launch_bounds__(512, 4) void k_gemm(
    const unsigned short* __restrict__ A, const unsigned short* __restrict__ Bt,
    const float* __restrict__ bias, unsigned short* __restrict__ Cb,
    float* __restrict__ sums, int M, int Nout, int ldc, int CT) {
  constexpr int T = K / 32;
  __shared__ __align__(16) unsigned short smem[24576];  // 3 x (A 4096 | B 4096) shorts = 48 KB

  int nwg = gridDim.x;
  int q = nwg >> 3, r8 = nwg & 7;
  int xcd = blockIdx.x & 7, oidx = blockIdx.x >> 3;
  int wid = (xcd < r8 ? xcd * (q + 1) : r8 * (q + 1) + (xcd - r8) * q) + oidx;
  int ct = wid % CT, rt = wid / CT;
  const int rowBase = rt * 128, colBase = ct * 128;

  const int tid = threadIdx.x, lane = tid & 63, wave = tid >> 6;  // 8 waves
  const int wm = wave >> 2, wn = wave & 3;  // 2 x 4
  const int l15 = lane & 15, lg = lane >> 4;

  unsigned short* Asm = smem;          // [3][128r][4 chunks][8]
  unsigned short* Bsm = smem + 12288;

  auto stage = [&](int s, int t) {
    int rr = tid >> 2;
    int cdat = (tid & 3) ^ ((rr >> 1) & 3);  // inverse-swizzled source chunk
    int gr = rowBase + rr; if (gr >= M) gr = M - 1;
    gld_lds16(A + (size_t)gr * K + t * 32 + cdat * 8, Asm + s * 4096 + (size_t)tid * 8);
    gld_lds16(Bt + (size_t)(colBase + rr) * K + t * 32 + cdat * 8, Bsm + s * 4096 + (size_t)tid * 8);
  };

  f32x4 acc[4][2] = {};
  stage(0, 0);
  stage(1, 1);
#pragma unroll
  for (int t = 0; t < T; ++t) {
    if (t + 1 < T) asm volatile("s_waitcnt vmcnt(2)" ::: "memory");
    else           asm volatile("s_waitcnt vmcnt(0)" ::: "memory");
    __builtin_amdgcn_s_barrier();
    __builtin_amdgcn_sched_barrier(0);
    const unsigned short* bA = Asm + (t % 3) * 4096;
    const unsigned short* bB = Bsm + (t % 3) * 4096;
    s16x8 af[4], bf[2];
#pragma unroll
    for (int i = 0; i < 4; ++i) {
      int ra = wm * 64 + i * 16 + l15;
      af[i] = *(const s16x8*)(bA + ((size_t)ra * 4 + (lg ^ ((ra >> 1) & 3))) * 8);
    }
#pragma unroll
    for (int i = 0; i < 2; ++i) {
      int rb = wn * 32 + i * 16 + l15;
      bf[i] = *(const s16x8*)(bB + ((size_t)rb * 4 + (lg ^ ((rb >> 1) & 3))) * 8);
    }
    if (t + 2 < T) stage((t + 2) % 3, t + 2);
#pragma unroll
    for (int mi = 0; mi < 4; ++mi)
#pragma unroll
      for (int ni = 0; ni < 2; ++ni)
        acc[mi][ni] = __builtin_amdgcn_mfma_f32_16x16x32_bf16(af[mi], bf[ni], acc[mi][ni], 0, 0, 0);
  }

  // epilogue: direct u16 stores
  float bnS[2] = {0.f, 0.f}, bnQ[2] = {0.f, 0.f};
#pragma unroll
  for (int ni = 0; ni < 2; ++ni) {
    int col = colBase + wn * 32 + ni * 16 + l15;
    if (col >= (EPI ? ldc : Nout)) continue;  // gemm2: skip dead pad cols
    bool inN = col < Nout;
    float bv = inN ? bias[col] : 0.f;
#pragma unroll
    for (int mi = 0; mi < 4; ++mi) {
      int row0 = rowBase + wm * 64 + mi * 16 + lg * 4;
#pragma unroll
      for (int rr = 0; rr < 4; ++rr) {
        int row = row0 + rr;
        if (row < M) {
          float v = inN ? acc[mi][ni][rr] + bv : 0.f;
          if (EPI) v = fmaxf(v, 0.f);
          else { bnS[ni] += v; bnQ[ni] += v * v; }
          Cb[(size_t)row * ldc + col] = f2b(v);
        }
      }
    }
  }
  if (!EPI) {
#pragma unroll
    for (int ni = 0; ni < 2; ++ni) {
      float cs = bnS[ni], cq = bnQ[ni];
      cs += __shfl_xor(cs, 16); cq += __shfl_xor(cq, 16);
      cs += __shfl_xor(cs, 32); cq += __shfl_xor(cq, 32);
      int col = colBase + wn * 32 + ni * 16 + l15;
      if (lg == 0 && col < Nout) {
        atomicAdd(&sums[col], cs);
        atomicAdd(&sums[D + col], cq);
      }
    }
  }
}

// ---------------- BatchNorm finalize ----------------
__global__ void k_bnfinal(const float* __restrict__ sums, const float* __restrict__ sumsq,
                          const float* __restrict__ gamma, const float* __restrict__ beta,
                          float* __restrict__ scale, float* __restrict__ shift, int N) {
  int c = threadIdx.x;
  if (c >= D) return;
  float inv = 1.f / (float)N;
  float mean = sums[c] * inv;
  float var = sumsq[c] * inv - mean * mean;
  if (var < 0.f) var = 0.f;
  float sc = gamma[c] * rsqrtf(var + 1e-5f);
  scale[c] = sc;
  shift[c] = beta[c] - mean * sc;
}

// ---------------- outputs (BN of last layer fused; no relu), vectorized ----------------
__global__ void k_pool(const unsigned short* __restrict__ hb, const float* __restrict__ scale,
                       const float* __restrict__ shift, const int* __restrict__ gs,
                       const int* __restrict__ gc, float* __restrict__ pooled, int total /* B*75 */) {
  int gid = blockIdx.x * blockDim.x + threadIdx.x;
  if (gid >= total) return;
  int g = gid / 75, c4 = (gid - g * 75) * 4;
  int start = gs[g], cnt = gc[g];
  f32x4 s = {0.f, 0.f, 0.f, 0.f};
  for (int i = 0; i < cnt; ++i) {
    s16x4 in = *(const s16x4*)(hb + (size_t)(start + i) * K1P + c4);
#pragma unroll
    for (int j = 0; j < 4; ++j) s[j] += b2f((unsigned short)in[j]);
  }
  f32x4 sc = *(const f32x4*)(scale + c4);
  f32x4 sh = *(const f32x4*)(shift + c4);
  float dv = (cnt > 0) ? (float)cnt : 1.f;
  f32x4 out;
#pragma unroll
  for (int j = 0; j < 4; ++j) out[j] = (s[j] * sc[j] + sh[j] * (float)cnt) / dv;
  *(f32x4*)(pooled + (size_t)g * D + c4) = out;
}

__global__ void k_nf(const unsigned short* __restrict__ hb, const float* __restrict__ scale,
                     const float* __restrict__ shift, const int* __restrict__ gs,
                     const int* __restrict__ gc, float* __restrict__ nf, float* __restrict__ mask) {
  int g = blockIdx.x;
  int start = gs[g], cnt = gc[g];
  int lim = cnt < MAXLEN ? cnt : MAXLEN;
  for (int idx = threadIdx.x; idx < MAXLEN * 75; idx += 256) {
    int p = idx / 75;
    int c4 = (idx - p * 75) * 4;
    f32x4 v = {0.f, 0.f, 0.f, 0.f};
    if (p < lim) {
      s16x4 in = *(const s16x4*)(hb + (size_t)(start + p) * K1P + c4);
      f32x4 sc = *(const f32x4*)(scale + c4);
      f32x4 sh = *(const f32x4*)(shift + c4);
#pragma unroll
      for (int j = 0; j < 4; ++j) v[j] = b2f((unsigned short)in[j]) * sc[j] + sh[j];
    }
    *(f32x4*)(nf + (size_t)g * (MAXLEN * D) + p * D + c4) = v;
  }
  if (threadIdx.x < MAXLEN) mask[(size_t)g * MAXLEN + threadIdx.x] = (threadIdx.x < lim) ? 1.f : 0.f;
}

extern "C" void kernel_launch(void* const* d_in, const int* in_sizes, int n_in,
                              void* d_out, int out_size, void* d_ws, size_t ws_size,
                              hipStream_t stream) {
  const int* x      = (const int*)d_in[0];
  const int* ei     = (const int*)d_in[1];   // [2][E]: src = ei, dst = ei+E
  const int* ea     = (const int*)d_in[2];   // [E][2]
  const int* batch  = (const int*)d_in[3];
  const float* xe1  = (const float*)d_in[5];
  const float* xe2  = (const float*)d_in[6];
  const float* ee1  = (const float*)d_in[7]; // [L][6][D]
  const float* ee2  = (const float*)d_in[8]; // [L][3][D]
  const float* W1   = (const float*)d_in[9];
  const float* b1   = (const float*)d_in[10];
  const float* W2   = (const float*)d_in[11];
  const float* b2   = (const float*)d_in[12];
  const float* gamma = (const float*)d_in[13];
  const float* beta  = (const float*)d_in[14];

  const int N = in_sizes[0] / 2;
  const int E = in_sizes[1] / 2;
  const int L = in_sizes[9] / (D * 2 * D);
  const int B = out_size / (D + MAXLEN * D + MAXLEN);

  char* ws = (char*)d_ws;
  size_t off = 0;
  auto alloc = [&](size_t bytes) -> void* {
    void* p = ws + off;
    off += (bytes + 255) & ~(size_t)255;
    return p;
  };
  unsigned short* aggbf = (unsigned short*)alloc((size_t)N * K1P * 2);
  unsigned short* hb    = (unsigned short*)alloc((size_t)N * K1P * 2);
  unsigned short* hid   = (unsigned short*)alloc((size_t)N * H1P * 2);
  unsigned short* cmb   = (unsigned short*)alloc((size_t)360 * K1P * 2);
  unsigned short* W1tA = (unsigned short*)alloc((size_t)L * W1ROWS * K1P * 2);
  unsigned short* W2tA = (unsigned short*)alloc((size_t)L * W2ROWS * H1P * 2);
  int* cnt    = (int*)alloc((size_t)N * 4);
  int* cur    = (int*)alloc((size_t)N * 4);
  int* offs   = (int*)alloc((size_t)(N + 1) * 4);
  int* cid    = (int*)alloc((size_t)N * 4);
  int* cnt18  = (int*)alloc((size_t)N * 18 * 4);
  int* ssrc   = (int*)alloc((size_t)E * 4);
  int* scid   = (int*)alloc((size_t)E * 4);
  int* gc     = (int*)alloc((size_t)B * 4);
  int* gs     = (int*)alloc((size_t)(B + 1) * 4);
  int* part   = (int*)alloc(1024 * 4);
  float* sumsA = (float*)alloc((size_t)L * 2 * D * 4);
  float* scale = (float*)alloc(2 * D * 4);  // scale | shift

  hipMemsetAsync(cnt, 0, (size_t)N * 4, stream);
  hipMemsetAsync(cur, 0, (size_t)N * 4, stream);
  hipMemsetAsync(gc, 0, (size_t)B * 4, stream);
  hipMemsetAsync(cnt18, 0, (size_t)N * 18 * 4, stream);
  hipMemsetAsync(sumsA, 0, (size_t)L * 2 * D * 4, stream);

  k_cmb<<<(360 * 75 + 255) / 256, 256, 0, stream>>>(xe1, xe2, cmb, 360 * 75);
  k_cid<<<(N + 255) / 256, 256, 0, stream>>>(x, cid, N);
  k_count<<<(E + 255) / 256, 256, 0, stream>>>(ei + E, cnt, E);
  {
    int P = (N + 1023) / 1024;
    k_scan1<<<P, 256, 0, stream>>>(cnt, part, N);
    k_scan2<<<1, 1024, 0, stream>>>(part, P);
    k_scan3<<<P, 256, 0, stream>>>(cnt, part, offs, N, P);
  }
  k_fill<<<(E + 255) / 256, 256, 0, stream>>>(ei, ei + E, ea, cid, cur, offs, ssrc, scid, cnt18, E);
  k_cnt18bf<<<(N * 10 + 255) / 256, 256, 0, stream>>>(cnt18, aggbf, N);
  k_count<<<(N + 255) / 256, 256, 0, stream>>>(batch, gc, N);
  {
    int P = (B + 1023) / 1024;
    k_scan1<<<P, 256, 0, stream>>>(gc, part, B);
    k_scan2<<<1, 1024, 0, stream>>>(part, P);
    k_scan3<<<P, 256, 0, stream>>>(gc, part, gs, B, P);
  }
  for (int l = 0; l < L; ++l) {
    k_wconv<<<(W1ROWS * K1P + 255) / 256, 256, 0, stream>>>(
        W1 + (size_t)l * D * H1, W1tA + (size_t)l * W1ROWS * K1P, D, H1, K1P, W1ROWS * K1P);
    k_wconv<<<(W2ROWS * H1P + 255) / 256, 256, 0, stream>>>(
        W2 + (size_t)l * H1 * D, W2tA + (size_t)l * W2ROWS * H1P, H1, D, H1P, W2ROWS * H1P);
  }
  k_ecw1<<<(L * H1 * 18 + 255) / 256, 256, 0, stream>>>(ee1, ee2, W1, W1tA, L, L * H1 * 18);

  const int RT = (N + 127) / 128;
  for (int l = 0; l < L; ++l) {
    float* sums = sumsA + (size_t)l * 2 * D;
    if (l == 0)
      k_agg<0><<<(N + 3) / 4, 256, 0, stream>>>(cmb, scid, offs, nullptr, nullptr, cid, aggbf, N);
    else
      k_agg<1><<<(N + 3) / 4, 256, 0, stream>>>(hb, ssrc, offs, scale, scale + D, nullptr, aggbf, N);
    k_gemm<K1P, 1><<<5 * RT, 512, 0, stream>>>(
        aggbf, W1tA + (size_t)l * W1ROWS * K1P, b1 + (size_t)l * H1, hid, nullptr, N, H1, H1P, 5);
    k_gemm<H1P, 0><<<3 * RT, 512, 0, stream>>>(
        hid, W2tA + (size_t)l * W2ROWS * H1P, b2 + (size_t)l * D, hb, sums, N, D, K1P, 3);
    k_bnfinal<<<1, 320, 0, stream>>>(sums, sums + D, gamma + (size_t)l * D, beta + (size_t)l * D,
                                     scale, scale + D, N);
  }

  float* out = (float*)d_out;
  float* out_pooled = out;
  float* out_nf = out + (size_t)B * D;
  float* out_mask = out + (size_t)B * D + (size_t)B * MAXLEN * D;
  k_pool<<<(B * 75 + 255) / 256, 256, 0, stream>>>(hb, scale, scale + D, gs, gc, out_pooled, B * 75);
  k_nf<<<B, 256, 0, stream>>>(hb, scale, scale + D, gs, gc, out_nf, out_mask);
}